// Round 3
// baseline (174.133 us; speedup 1.0000x reference)
//
#include <hip/hip_runtime.h>

// ---------------------------------------------------------------------------
// MalConv fused: GEMM M=16000, K=4000, N=256 (W1||W2) bf16 MFMA 16x16x32,
// epilogue GLU+relu+segmented-max in registers, then tiny FC.
//
// Round-3: ZERO barriers in the K-loop. A-fragment for lane (l16,quad) is
// exactly one 16B emb row chosen by one x byte -> per-lane ds_read_b128 from
// a 4KB LDS emb table (no A staging, no ping-pong). B goes global->reg,
// prefetched 1 kt ahead; x prefetched 2 kt ahead. Each wave owns matching
// W1/W2 column blocks so GLU is pure register math (no epilogue exchange).
// Wave tile: 32M x 32o-pairs (mi=2; ni=0,1 -> W1 cols, ni=2,3 -> W2 cols).
// ---------------------------------------------------------------------------

typedef __attribute__((ext_vector_type(8))) short short8;
typedef __attribute__((ext_vector_type(4))) float f32x4;

__device__ __forceinline__ unsigned short f2b(float f) {
    union { float f; unsigned u; } un;
    un.f = f;
    unsigned u = un.u;
    return (unsigned short)((u + 0x7FFFu + ((u >> 16) & 1u)) >> 16);  // RNE
}

#define KT_COUNT 125                              // K = 4000 = 125 * 32
#define WS_BBLK_BYTES (KT_COUNT * 256 * 32 * 2)   // 2,048,000 B bf16 weights
#define WS_MWS_OFF WS_BBLK_BYTES                  // 8*128 f32 max accumulator

// Pack W1,W2 (fp32 [128][8][500]) -> bf16 Bblk[kt][o][j]  (r=kt*32+j, k=r>>3,
// c=r&7). One uint4 per thread; coalesced writes. Also zeros m_ws.
__global__ __launch_bounds__(256) void prep_weights(
        const float* __restrict__ W1, const float* __restrict__ W2,
        unsigned short* __restrict__ Bblk, float* __restrict__ m_ws) {
    int u   = blockIdx.x * 256 + threadIdx.x;     // 0 .. 127,999 (uint4 idx)
    int kt  = u >> 10;
    int rem = u & 1023;
    int o   = rem >> 2;                           // 0..255
    int g   = rem & 3;
    int k   = kt * 4 + g;                         // 0..499
    const float* W = (o < 128) ? W1 : W2;
    int oo = o & 127;
    unsigned short v[8];
#pragma unroll
    for (int c = 0; c < 8; ++c) v[c] = f2b(W[oo * 4000 + c * 500 + k]);
    uint4 pack;
    pack.x = (unsigned)v[0] | ((unsigned)v[1] << 16);
    pack.y = (unsigned)v[2] | ((unsigned)v[3] << 16);
    pack.z = (unsigned)v[4] | ((unsigned)v[5] << 16);
    pack.w = (unsigned)v[6] | ((unsigned)v[7] << 16);
    *(uint4*)&Bblk[u * 8] = pack;
    if (blockIdx.x < 4) m_ws[blockIdx.x * 256 + threadIdx.x] = 0.f;
}

// 250 WGs x 512 threads; WG tile 64M x 256N. Wave w: mq=w>>2 (32 rows),
// nq=w&3 (32 o-columns, W1 block + matching W2 block for register GLU).
__global__ __launch_bounds__(512, 2) void malconv_main(
        const int* __restrict__ x, const float* __restrict__ emb,
        const float* __restrict__ b1, const float* __restrict__ b2,
        const unsigned short* __restrict__ Bblk, float* __restrict__ m_ws) {
    __shared__ __align__(16) unsigned short embb[257 * 8];   // 4.1 KB bf16 emb

    const int t = threadIdx.x;
    for (int e = t; e < 257 * 8; e += 512) embb[e] = f2b(emb[e]);
    __syncthreads();   // the ONLY barrier in this kernel

    const int m0   = blockIdx.x * 64;
    const int lane = t & 63, wave = t >> 6;
    const int quad = lane >> 4, l16 = lane & 15;
    const int mq   = wave >> 2, nq = wave & 3;

    // per-lane x pointers for the two A fragments (rows mq*32 + mi*16 + l16,
    // k position = kt*4 + quad)
    const int* xp0 = x + (m0 + mq * 32 + l16) * 500 + quad;
    const int* xp1 = xp0 + 16 * 500;

    // B fragment base: W1 rows o = nq*32 + l16 (+512 shorts for ni=1);
    // W2 at +128*32 = +4096 shorts. kt stride = 8192 shorts.
    const unsigned short* bbase = Bblk + (nq * 32 + l16) * 32 + quad * 8;

    f32x4 acc[2][4];
#pragma unroll
    for (int mi = 0; mi < 2; ++mi)
#pragma unroll
        for (int ni = 0; ni < 4; ++ni) {
            f32x4 z = {0.f, 0.f, 0.f, 0.f};
            acc[mi][ni] = z;
        }

    // preload: x for kt=0,1; B for kt=0
    int xc0 = xp0[0], xc1 = xp1[0];
    int xn0 = xp0[4], xn1 = xp1[4];
    short8 bcur[4];
    bcur[0] = *(const short8*)(bbase);
    bcur[1] = *(const short8*)(bbase + 512);
    bcur[2] = *(const short8*)(bbase + 4096);
    bcur[3] = *(const short8*)(bbase + 4608);

#pragma unroll 5
    for (int kt = 0; kt < KT_COUNT; ++kt) {
        // prefetch x two ahead, B one ahead (clamped indices keep it uniform
        // and in-bounds; tail re-loads are harmless)
        int ktf = kt + 2; if (ktf > KT_COUNT - 1) ktf = KT_COUNT - 1;
        int ktb = kt + 1; if (ktb > KT_COUNT - 1) ktb = KT_COUNT - 1;
        int xf0 = xp0[ktf * 4];
        int xf1 = xp1[ktf * 4];
        const unsigned short* bb = bbase + ktb * 8192;
        short8 bnxt[4];
        bnxt[0] = *(const short8*)(bb);
        bnxt[1] = *(const short8*)(bb + 512);
        bnxt[2] = *(const short8*)(bb + 4096);
        bnxt[3] = *(const short8*)(bb + 4608);
        // per-lane A gather from LDS emb table (x values loaded 2 iters ago)
        short8 a0 = *(const short8*)&embb[xc0 * 8];
        short8 a1 = *(const short8*)&embb[xc1 * 8];
#pragma unroll
        for (int ni = 0; ni < 4; ++ni) {
            acc[0][ni] = __builtin_amdgcn_mfma_f32_16x16x32_bf16(
                a0, bcur[ni], acc[0][ni], 0, 0, 0);
            acc[1][ni] = __builtin_amdgcn_mfma_f32_16x16x32_bf16(
                a1, bcur[ni], acc[1][ni], 0, 0, 0);
        }
        // rotate pipeline registers
        xc0 = xn0; xc1 = xn1; xn0 = xf0; xn1 = xf1;
#pragma unroll
        for (int ni = 0; ni < 4; ++ni) bcur[ni] = bnxt[ni];
    }

    // ---- epilogue: register GLU + segmented max, no barrier ----
    const int b0 = m0 / 2000;
    const int bsplit = (b0 + 1) * 2000;          // first patch of batch b0+1
    const bool crosses = (m0 + 63) >= bsplit;
#pragma unroll
    for (int ni = 0; ni < 2; ++ni) {
        int o = nq * 32 + ni * 16 + l16;
        float bb1 = b1[o], bb2 = b2[o];
        float mx0 = 0.f, mx1 = 0.f;              // h >= 0 always
#pragma unroll
        for (int mi = 0; mi < 2; ++mi)
#pragma unroll
            for (int r = 0; r < 4; ++r) {
                int ml = mq * 32 + mi * 16 + quad * 4 + r;
                float g1 = acc[mi][ni][r] + bb1;       // W1 frag
                float g2 = acc[mi][ni + 2][r] + bb2;   // matching W2 frag
                float h = fmaxf(g1 / (1.f + __expf(-g2)), 0.f);
                if (m0 + ml >= bsplit) mx1 = fmaxf(mx1, h);
                else                   mx0 = fmaxf(mx0, h);
            }
        // reduce across the 4 quads (same o, different rows)
        mx0 = fmaxf(mx0, __shfl_xor(mx0, 16));
        mx0 = fmaxf(mx0, __shfl_xor(mx0, 32));
        mx1 = fmaxf(mx1, __shfl_xor(mx1, 16));
        mx1 = fmaxf(mx1, __shfl_xor(mx1, 32));
        if (quad == 0) {
            // nonneg floats: int compare == float compare
            atomicMax((int*)&m_ws[b0 * 128 + o], __float_as_int(mx0));
            if (crosses)
                atomicMax((int*)&m_ws[(b0 + 1) * 128 + o], __float_as_int(mx1));
        }
    }
}

// out[b][j] = sum_o m_ws[b][o] * fcW[j][o] + fcb[j]   (16 outputs)
__global__ void fc_kernel(const float* __restrict__ m_ws,
                          const float* __restrict__ fcW,
                          const float* __restrict__ fcb,
                          float* __restrict__ out) {
    int t = threadIdx.x;
    if (t < 16) {
        int b = t >> 1, j = t & 1;
        float s = 0.f;
        for (int o = 0; o < 128; ++o) s += m_ws[b * 128 + o] * fcW[j * 128 + o];
        out[t] = s + fcb[j];
    }
}

extern "C" void kernel_launch(void* const* d_in, const int* in_sizes, int n_in,
                              void* d_out, int out_size, void* d_ws, size_t ws_size,
                              hipStream_t stream) {
    const int*   x   = (const int*)d_in[0];     // [8, 1e6] values 0..256
    const float* emb = (const float*)d_in[1];   // [257, 8]
    const float* W1  = (const float*)d_in[2];   // [128, 8, 500]
    const float* b1  = (const float*)d_in[3];   // [128]
    const float* W2  = (const float*)d_in[4];   // [128, 8, 500]
    const float* b2  = (const float*)d_in[5];   // [128]
    const float* fcW = (const float*)d_in[6];   // [2, 128]
    const float* fcb = (const float*)d_in[7];   // [2]
    float* out = (float*)d_out;                 // [8, 2]

    unsigned short* Bblk = (unsigned short*)d_ws;
    float* m_ws = (float*)((char*)d_ws + WS_MWS_OFF);

    prep_weights<<<500, 256, 0, stream>>>(W1, W2, Bblk, m_ws);
    malconv_main<<<250, 512, 0, stream>>>(x, emb, b1, b2, Bblk, m_ws);
    fc_kernel<<<1, 64, 0, stream>>>(m_ws, fcW, fcb, out);
}